// Round 4
// baseline (457.747 us; speedup 1.0000x reference)
//
#include <hip/hip_runtime.h>
#include <math.h>

typedef unsigned short u16;
typedef unsigned int u32;
typedef __bf16 bf16x8 __attribute__((ext_vector_type(8)));
typedef float f32x4 __attribute__((ext_vector_type(4)));

#define NB 1024   // batch
#define HID 1024

__device__ __forceinline__ float bfu(u16 u) { return __uint_as_float(((u32)u) << 16); }
__device__ __forceinline__ u16 f2bf(float f) {
    u32 u = __float_as_uint(f);
    return (u16)((u + 0x7fffu + ((u >> 16) & 1u)) >> 16);
}
__device__ __forceinline__ u32 pack2(float a, float b) {
    return (u32)f2bf(a) | ((u32)f2bf(b) << 16);
}
__device__ __forceinline__ void unpack8(uint4 v, float* f) {
    f[0] = bfu((u16)(v.x & 0xffffu)); f[1] = bfu((u16)(v.x >> 16));
    f[2] = bfu((u16)(v.y & 0xffffu)); f[3] = bfu((u16)(v.y >> 16));
    f[4] = bfu((u16)(v.z & 0xffffu)); f[5] = bfu((u16)(v.z >> 16));
    f[6] = bfu((u16)(v.w & 0xffffu)); f[7] = bfu((u16)(v.w >> 16));
}

#if __has_builtin(__builtin_amdgcn_global_load_lds)
#define HAVE_GLL 1
#else
#define HAVE_GLL 0
#endif

// Stage 16B per lane: global -> LDS. ldsbase must be wave-uniform; HW (or
// fallback) writes to ldsbase + lane*16.
__device__ __forceinline__ void stage16(const void* g, void* ldsbase, int lane) {
#if HAVE_GLL
    typedef const __attribute__((address_space(1))) unsigned char ga_t;
    typedef __attribute__((address_space(3))) unsigned char la_t;
    __builtin_amdgcn_global_load_lds((ga_t*)(unsigned long long)g,
                                     (la_t*)(u32)(unsigned long long)ldsbase,
                                     16, 0, 0);
#else
    *reinterpret_cast<uint4*>((char*)ldsbase + lane * 16) =
        *reinterpret_cast<const uint4*>(g);
#endif
}

// ---------------- 128x128-tile helpers (4 waves, 2x2) -------------------

__device__ __forceinline__ void stage_tile(const u16* src, int ld, u16* dst, int tid) {
    int w = tid >> 6, lane = tid & 63;
#pragma unroll
    for (int q = 0; q < 4; ++q) {
        int rbase = q * 32 + w * 8;
        int row = rbase + (lane >> 3);
        stage16(src + (size_t)row * ld + (lane & 7) * 8, dst + rbase * 64, lane);
    }
}

__device__ __forceinline__ void mfma_block(const u16* As, const u16* Bs,
                                           f32x4 acc[4][4], int wr, int wc, int lane) {
    int lr = lane >> 4, lc = lane & 15;
#pragma unroll
    for (int kc = 0; kc < 64; kc += 32) {
        bf16x8 av[4], bv[4];
#pragma unroll
        for (int it = 0; it < 4; ++it)
            av[it] = *(const bf16x8*)&As[(wr * 64 + it * 16 + lc) * 64 + kc + lr * 8];
#pragma unroll
        for (int nt = 0; nt < 4; ++nt)
            bv[nt] = *(const bf16x8*)&Bs[(wc * 64 + nt * 16 + lc) * 64 + kc + lr * 8];
#pragma unroll
        for (int it = 0; it < 4; ++it)
#pragma unroll
            for (int nt = 0; nt < 4; ++nt)
                acc[it][nt] = __builtin_amdgcn_mfma_f32_16x16x32_bf16(
                    av[it], bv[nt], acc[it][nt], 0, 0, 0);
    }
}

// ---------------------------- prep kernels ------------------------------

__global__ __launch_bounds__(256) void k_cast(const float* in, u16* out, int n) {
    int i = blockIdx.x * 256 + threadIdx.x;
    if (i < n) out[i] = f2bf(in[i]);
}

__global__ __launch_bounds__(256) void k_transposeB(const float* inA, const float* inB,
                                                    u16* outA, u16* outB, int R, int C) {
    const float* in = blockIdx.z ? inB : inA;
    u16* out = blockIdx.z ? outB : outA;
    __shared__ u16 tile[32][33];
    int c0 = blockIdx.x * 32, r0 = blockIdx.y * 32;
    int tx = threadIdx.x, ty = threadIdx.y;  // (32, 8)
#pragma unroll
    for (int dy = 0; dy < 32; dy += 8)
        tile[ty + dy][tx] = f2bf(in[(size_t)(r0 + ty + dy) * C + c0 + tx]);
    __syncthreads();
#pragma unroll
    for (int dy = 0; dy < 32; dy += 8)
        out[(size_t)(c0 + ty + dy) * R + r0 + tx] = tile[tx][ty + dy];
}

__global__ __launch_bounds__(256) void k_layer1(const float* states, const float* tptr,
                                                const float* dW1, const float* db1,
                                                const float* nW1, const float* nb1,
                                                u16* h1d, u16* h1n, u16* g1d) {
    __shared__ float xt[129][8];
    int blk = blockIdx.x, q = blockIdx.y, net = blockIdx.z, tid = threadIdx.x;
    float t = *tptr;
    for (int idx = tid; idx < 8 * 128; idx += 256) {
        int d = idx >> 3, s = idx & 7;
        xt[d][s] = states[(size_t)(blk * 8 + s) * 256 + d];
    }
    if (tid < 8) xt[128][tid] = t;
    __syncthreads();
    const float* W = net ? nW1 : dW1;
    const float* bi = net ? nb1 : db1;
    u16* H = net ? h1n : h1d;
    int o = q * 256 + tid;
    float acc[8] = {0.f, 0.f, 0.f, 0.f, 0.f, 0.f, 0.f, 0.f};
    for (int d = 0; d < 129; ++d) {
        float w = W[(size_t)d * 1024 + o];
        float4 xa = *(const float4*)&xt[d][0];
        float4 xb = *(const float4*)&xt[d][4];
        acc[0] += xa.x * w; acc[1] += xa.y * w; acc[2] += xa.z * w; acc[3] += xa.w * w;
        acc[4] += xb.x * w; acc[5] += xb.y * w; acc[6] += xb.z * w; acc[7] += xb.w * w;
    }
    float b = bi[o];
#pragma unroll
    for (int s = 0; s < 8; ++s) {
        float h = tanhf(acc[s] + b);
        H[(size_t)(blk * 8 + s) * 1024 + o] = f2bf(h);
        if (!net) g1d[(size_t)(blk * 8 + s) * 1024 + o] = f2bf(1.f - h * h);
    }
}

__global__ __launch_bounds__(256) void k_l2part(const u16* Ad, const u16* An,
                                                const u16* Wd, const u16* Wn,
                                                float* P) {
    int x = blockIdx.x;
    int nt = x & 7, ks = x >> 3;
    int mt = blockIdx.y, net = blockIdx.z;
    const u16* A = net ? An : Ad;
    const u16* W = net ? Wn : Wd;
    int n0 = nt * 128, row0 = mt * 128;
    int kbeg = ks * 512;
    __shared__ __align__(16) u16 As[128 * 64], Bs[128 * 64];
    int tid = threadIdx.x, w = tid >> 6, lane = tid & 63;
    int wr = w >> 1, wc = w & 1, lr = lane >> 4, lc = lane & 15;
    f32x4 acc[4][4];
#pragma unroll
    for (int a = 0; a < 4; ++a)
#pragma unroll
        for (int b2 = 0; b2 < 4; ++b2) { f32x4 zz = {0.f, 0.f, 0.f, 0.f}; acc[a][b2] = zz; }
    for (int k0 = kbeg; k0 < kbeg + 512; k0 += 64) {
        stage_tile(A + (size_t)row0 * 1024 + k0, 1024, As, tid);
        stage_tile(W + (size_t)n0 * 1024 + k0, 1024, Bs, tid);
        __syncthreads();
        mfma_block(As, Bs, acc, wr, wc, lane);
        __syncthreads();
    }
    float* dst = P + (size_t)(net * 2 + ks) * 1024 * 1024;
#pragma unroll
    for (int it = 0; it < 4; ++it)
#pragma unroll
        for (int nt2 = 0; nt2 < 4; ++nt2) {
            int col = n0 + wc * 64 + nt2 * 16 + lc;
#pragma unroll
            for (int r = 0; r < 4; ++r) {
                int row = row0 + wr * 64 + it * 16 + lr * 4 + r;
                dst[(size_t)row * 1024 + col] = acc[it][nt2][r];
            }
        }
}

__global__ __launch_bounds__(256) void k_h2fin(const float* P, const float* db2,
                                               const float* nb2, u16* h2d, u16* h2n) {
    int net = blockIdx.y;
    const float* b = net ? nb2 : db2;
    u16* H = net ? h2n : h2d;
    size_t idx = (size_t)blockIdx.x * 256 + threadIdx.x;  // < 1M
    int col = (int)(idx & 1023);
    const float* P0 = P + (size_t)(net * 2) * 1024 * 1024;
    const float* P1 = P + (size_t)(net * 2 + 1) * 1024 * 1024;
    H[idx] = f2bf(tanhf(P0[idx] + P1[idx] + b[col]));
}

__global__ __launch_bounds__(256) void k_l3part(const u16* Ad, const u16* An,
                                                const u16* Wd, const u16* Wn,
                                                float* P) {
    int ks = blockIdx.x, mt = blockIdx.y, net = blockIdx.z;
    const u16* A = net ? An : Ad;
    const u16* W = net ? Wn : Wd;
    int row0 = mt * 128, kbeg = ks * 256;
    __shared__ __align__(16) u16 As[128 * 64], Bs[128 * 64];
    int tid = threadIdx.x, w = tid >> 6, lane = tid & 63;
    int wr = w >> 1, wc = w & 1, lr = lane >> 4, lc = lane & 15;
    f32x4 acc[4][4];
#pragma unroll
    for (int a = 0; a < 4; ++a)
#pragma unroll
        for (int b2 = 0; b2 < 4; ++b2) { f32x4 zz = {0.f, 0.f, 0.f, 0.f}; acc[a][b2] = zz; }
    for (int k0 = kbeg; k0 < kbeg + 256; k0 += 64) {
        stage_tile(A + (size_t)row0 * 1024 + k0, 1024, As, tid);
        stage_tile(W + (size_t)k0, 1024, Bs, tid);
        __syncthreads();
        mfma_block(As, Bs, acc, wr, wc, lane);
        __syncthreads();
    }
    float* dst = P + (size_t)(net * 4 + ks) * 1024 * 128;
#pragma unroll
    for (int it = 0; it < 4; ++it)
#pragma unroll
        for (int nt2 = 0; nt2 < 4; ++nt2) {
            int col = wc * 64 + nt2 * 16 + lc;
#pragma unroll
            for (int r = 0; r < 4; ++r) {
                int row = row0 + wr * 64 + it * 16 + lr * 4 + r;
                dst[(size_t)row * 128 + col] = acc[it][nt2][r];
            }
        }
}

__global__ __launch_bounds__(256) void k_scaleA(const u16* dW1bf, const u16* g1d,
                                                u16* Asc, int c0) {
    int sl = blockIdx.x;
    size_t b = (size_t)(c0 + sl);
    const u16* g1 = g1d + b * 1024;
    u16* dst = Asc + (size_t)sl * (128 * 1024);
    int tid = threadIdx.x;
    for (int idx = tid; idx < 128 * 128; idx += 256) {
        int row = idx >> 7, jc = idx & 127;
        int j0 = jc * 8;
        uint4 wv = *(const uint4*)&dW1bf[(size_t)row * 1024 + j0];
        uint4 gv = *(const uint4*)&g1[j0];
        float wf[8], gf[8];
        unpack8(wv, wf);
        unpack8(gv, gf);
        uint4 o;
        o.x = pack2(wf[0] * gf[0], wf[1] * gf[1]);
        o.y = pack2(wf[2] * gf[2], wf[3] * gf[3]);
        o.z = pack2(wf[4] * gf[4], wf[5] * gf[5]);
        o.w = pack2(wf[6] * gf[6], wf[7] * gf[7]);
        *(uint4*)&dst[(size_t)row * 1024 + j0] = o;
    }
}

// ------------- 256x256 4-deep counted-vmcnt jac GEMM (BK=32) ------------
// 512 threads = 8 waves (2 M x 4 N). Per-wave output 128x64 (8x4 frags).
// LDS: 4 bufs x (A 256x32 + B 256x32) bf16 = 128 KiB.
// T2 swizzle (4 chunks/row): global SOURCE chunk c^(row&3), LDS linear via
// global_load_lds, ds_read chunk lr^(row&3). Slot-balanced (verified).
// T4: raw s_barrier (no vmcnt drain) + counted s_waitcnt vmcnt(8) -- tiles
// t+2, t+3 stay in flight across barriers. One barrier per K-step.

__global__ __launch_bounds__(512, 2) void k_jac256(const u16* Asc, const u16* W2T,
                                                   const u16* W3T, const u16* h2d,
                                                   float* Jpart, int c0, int CS) {
    __shared__ __align__(16) u16 smem[4][2][8192];
    int tid = threadIdx.x, lane = tid & 63, w = tid >> 6;
    int wr = w >> 2, wc = w & 3, lr = lane >> 4, lc = lane & 15;
    int nwg = 2 * CS;
    int hID = blockIdx.x;
    int lin = (hID & 7) * (nwg >> 3) + (hID >> 3);   // XCD-contiguous remap
    int mt = lin >> 2, nt = lin & 3;
    int n0 = nt * 256;
    const u16* Apanel = Asc + (size_t)mt * 256 * 1024;
    const u16* Bpanel = W2T + (size_t)n0 * 1024;

    f32x4 acc[8][4];
#pragma unroll
    for (int m = 0; m < 8; ++m)
#pragma unroll
        for (int n = 0; n < 4; ++n) { f32x4 zz = {0.f, 0.f, 0.f, 0.f}; acc[m][n] = zz; }

    // stage K-tile t (256x32 each of A and B); 4 loads/thread, FIFO: A,A,B,B
    auto stage = [&](int t) {
        int k0 = t * 32;
        u16* da = &smem[t & 3][0][0];
        u16* db = &smem[t & 3][1][0];
#pragma unroll
        for (int q = 0; q < 2; ++q) {
            int D = w * 128 + q * 64 + lane;          // 16B-chunk id 0..1023
            int r = D >> 2, c = D & 3;
            stage16(Apanel + (size_t)r * 1024 + k0 + ((c ^ (r & 3)) << 3),
                    da + (w * 128 + q * 64) * 8, lane);
        }
#pragma unroll
        for (int q = 0; q < 2; ++q) {
            int D = w * 128 + q * 64 + lane;
            int r = D >> 2, c = D & 3;
            stage16(Bpanel + (size_t)r * 1024 + k0 + ((c ^ (r & 3)) << 3),
                    db + (w * 128 + q * 64) * 8, lane);
        }
    };

    auto compute = [&](int t) {
        const u16* As = &smem[t & 3][0][0];
        const u16* Bs = &smem[t & 3][1][0];
        bf16x8 av[8], bv[4];
#pragma unroll
        for (int m = 0; m < 8; ++m) {
            int row = wr * 128 + m * 16 + lc;
            av[m] = *(const bf16x8*)&As[row * 32 + ((lr ^ (row & 3)) << 3)];
        }
#pragma unroll
        for (int n = 0; n < 4; ++n) {
            int row = wc * 64 + n * 16 + lc;
            bv[n] = *(const bf16x8*)&Bs[row * 32 + ((lr ^ (row & 3)) << 3)];
        }
        __builtin_amdgcn_s_setprio(1);
#pragma unroll
        for (int m = 0; m < 8; ++m)
#pragma unroll
            for (int n = 0; n < 4; ++n)
                acc[m][n] = __builtin_amdgcn_mfma_f32_16x16x32_bf16(
                    av[m], bv[n], acc[m][n], 0, 0, 0);
        __builtin_amdgcn_s_setprio(0);
    };

    // prologue: 3 tiles in flight, wait oldest
    stage(0); stage(1); stage(2);
    asm volatile("s_waitcnt vmcnt(8)" ::: "memory");
    __builtin_amdgcn_sched_barrier(0);
    __builtin_amdgcn_s_barrier();
    __builtin_amdgcn_sched_barrier(0);

    // main loop: compute(t) || stage(t+3); vmcnt(8) keeps t+2,t+3 in flight
    for (int t = 0; t < 29; ++t) {
        compute(t);
        __builtin_amdgcn_sched_barrier(0);
        stage(t + 3);
        asm volatile("s_waitcnt vmcnt(8)" ::: "memory");
        __builtin_amdgcn_sched_barrier(0);
        __builtin_amdgcn_s_barrier();
        __builtin_amdgcn_sched_barrier(0);
    }
    // tails: drain 8 -> 4 -> 0
    compute(29);
    __builtin_amdgcn_sched_barrier(0);
    asm volatile("s_waitcnt vmcnt(4)" ::: "memory");
    __builtin_amdgcn_sched_barrier(0);
    __builtin_amdgcn_s_barrier();
    __builtin_amdgcn_sched_barrier(0);
    compute(30);
    __builtin_amdgcn_sched_barrier(0);
    asm volatile("s_waitcnt vmcnt(0)" ::: "memory");
    __builtin_amdgcn_sched_barrier(0);
    __builtin_amdgcn_s_barrier();
    __builtin_amdgcn_sched_barrier(0);
    compute(31);

    // Fused diagonal contraction (unchanged mapping, r3-verified).
    int b = c0 + 2 * mt + wr;
    float g2v[4];
#pragma unroll
    for (int n = 0; n < 4; ++n) {
        int k2 = n0 + wc * 64 + n * 16 + lc;
        float h2 = bfu(h2d[(size_t)b * 1024 + k2]);
        g2v[n] = 1.f - h2 * h2;
    }
    float* jtmp = (float*)&smem[0][0][0];   // [4][256] floats; buf0 is idle
#pragma unroll
    for (int m = 0; m < 8; ++m) {
#pragma unroll
        for (int r = 0; r < 4; ++r) {
            int i = m * 16 + lr * 4 + r;
            float p = 0.f;
#pragma unroll
            for (int n = 0; n < 4; ++n) {
                int k2 = n0 + wc * 64 + n * 16 + lc;
                float w3 = bfu(W3T[(size_t)i * 1024 + k2]);
                p += acc[m][n][r] * g2v[n] * w3;
            }
#pragma unroll
            for (int msk = 1; msk < 16; msk <<= 1) p += __shfl_xor(p, msk, 64);
            if (lc == 0) jtmp[wc * 256 + wr * 128 + i] = p;
        }
    }
    __syncthreads();
    if (tid < 256) {
        float s = jtmp[tid] + jtmp[256 + tid] + jtmp[512 + tid] + jtmp[768 + tid];
        int bb = c0 + 2 * mt + (tid >> 7);
        Jpart[((size_t)bb * 4 + nt) * 128 + (tid & 127)] = s;
    }
}

// ------------------------------ finalize --------------------------------
__global__ __launch_bounds__(128) void k_final(const float* states, const float* Jpart,
                                               const float* L3part, const float* db3,
                                               const float* nb3, float* out) {
    int b = blockIdx.x, i = threadIdx.x;
    float jd = 0.f;
#pragma unroll
    for (int kb = 0; kb < 4; ++kb) jd += Jpart[((size_t)b * 4 + kb) * 128 + i];
    float mu = db3[i], qr = nb3[i];
#pragma unroll
    for (int ks = 0; ks < 4; ++ks) {
        mu += L3part[((size_t)(0 * 4 + ks) * 1024 + b) * 128 + i];
        qr += L3part[((size_t)(1 * 4 + ks) * 1024 + b) * 128 + i];
    }
    out[(size_t)b * 256 + i] = mu;
    float q = (qr > 20.f) ? qr : log1pf(expf(qr));
    float sig = states[(size_t)b * 256 + 128 + i];
    out[(size_t)b * 256 + 128 + i] = 2.f * jd * sig + q;
    float s1 = jd;
    float s2 = q / (sig + 1e-6f);
#pragma unroll
    for (int m = 32; m >= 1; m >>= 1) {
        s1 += __shfl_down(s1, m, 64);
        s2 += __shfl_down(s2, m, 64);
    }
    __shared__ float red[4];
    int wv = i >> 6, ln = i & 63;
    if (ln == 0) { red[wv * 2] = s1; red[wv * 2 + 1] = s2; }
    __syncthreads();
    if (i == 0) out[(size_t)NB * 256 + b] = -(red[0] + red[2]) + 0.5f * (red[1] + red[3]);
}

extern "C" void kernel_launch(void* const* d_in, const int* in_sizes, int n_in,
                              void* d_out, int out_size, void* d_ws, size_t ws_size,
                              hipStream_t stream) {
    (void)in_sizes; (void)n_in; (void)out_size;
    const float* states = (const float*)d_in[0];
    const float* tptr   = (const float*)d_in[1];
    const float* dW1 = (const float*)d_in[2];  const float* db1 = (const float*)d_in[3];
    const float* dW2 = (const float*)d_in[4];  const float* db2 = (const float*)d_in[5];
    const float* dW3 = (const float*)d_in[6];  const float* db3 = (const float*)d_in[7];
    const float* nW1 = (const float*)d_in[8];  const float* nb1 = (const float*)d_in[9];
    const float* nW2 = (const float*)d_in[10]; const float* nb2 = (const float*)d_in[11];
    const float* nW3 = (const float*)d_in[12]; const float* nb3 = (const float*)d_in[13];
    float* out = (float*)d_out;
    char* ws = (char*)d_ws;

    // workspace layout (bytes)
    u16* dW1bf = (u16*)(ws + 0);           //  128x1024 bf16     256 KiB
    u16* dW2T  = (u16*)(ws + 262144);      // 1024x1024 bf16 (T)   2 MiB
    u16* nW2T  = (u16*)(ws + 2359296);     //                      2 MiB
    u16* dW3T  = (u16*)(ws + 4456448);     //  128x1024 bf16 (T) 256 KiB
    u16* nW3T  = (u16*)(ws + 4718592);     //                    256 KiB
    u16* h1d   = (u16*)(ws + 4980736);     // 1024x1024 bf16       2 MiB
    u16* h1n   = (u16*)(ws + 7077888);
    u16* h2d   = (u16*)(ws + 9175040);
    u16* h2n   = (u16*)(ws + 11272192);
    u16* g1d   = (u16*)(ws + 13369344);    // 1024x1024 bf16       2 MiB
    float* Jpart  = (float*)(ws + 15466496);  // 1024x4x128 f32    2 MiB
    float* L3part = (float*)(ws + 17563648);  // 2x4x1024x128 f32  4 MiB
    float* H2part = (float*)(ws + 21757952);  // 2x2x1024x1024 f32 16 MiB
    u16* Asc   = (u16*)(ws + 38535168);    // CS x 128 x 1024 bf16 (chunked)
    const size_t ASC_OFF = 38535168;

    int CS = 1024;
    while (CS > 64 && ASC_OFF + (size_t)CS * 262144 > ws_size) CS >>= 1;

    k_cast<<<512, 256, 0, stream>>>(dW1, dW1bf, 128 * 1024);
    dim3 tb(32, 8);
    k_transposeB<<<dim3(32, 32, 2), tb, 0, stream>>>(dW2, nW2, dW2T, nW2T, 1024, 1024);
    k_transposeB<<<dim3(4, 32, 2), tb, 0, stream>>>(dW3, nW3, dW3T, nW3T, 1024, 128);
    k_layer1<<<dim3(128, 4, 2), 256, 0, stream>>>(states, tptr, dW1, db1, nW1, nb1,
                                                  h1d, h1n, g1d);
    k_l2part<<<dim3(16, 8, 2), 256, 0, stream>>>(h1d, h1n, dW2T, nW2T, H2part);
    k_h2fin<<<dim3(4096, 2), 256, 0, stream>>>(H2part, db2, nb2, h2d, h2n);
    k_l3part<<<dim3(4, 8, 2), 256, 0, stream>>>(h2d, h2n, dW3T, nW3T, L3part);
    for (int c0 = 0; c0 < NB; c0 += CS) {
        k_scaleA<<<CS, 256, 0, stream>>>(dW1bf, g1d, Asc, c0);
        k_jac256<<<2 * CS, 512, 0, stream>>>(Asc, dW2T, dW3T, h2d, Jpart, c0, CS);
    }
    k_final<<<1024, 128, 0, stream>>>(states, Jpart, L3part, db3, nb3, out);
}

// Round 5
// 444.693 us; speedup vs baseline: 1.0294x; 1.0294x over previous
//
#include <hip/hip_runtime.h>
#include <math.h>

typedef unsigned short u16;
typedef unsigned int u32;
typedef __bf16 bf16x8 __attribute__((ext_vector_type(8)));
typedef float f32x4 __attribute__((ext_vector_type(4)));

#define NB 1024   // batch
#define HID 1024

__device__ __forceinline__ float bfu(u16 u) { return __uint_as_float(((u32)u) << 16); }
__device__ __forceinline__ u16 f2bf(float f) {
    u32 u = __float_as_uint(f);
    return (u16)((u + 0x7fffu + ((u >> 16) & 1u)) >> 16);
}
__device__ __forceinline__ u32 pack2(float a, float b) {
    return (u32)f2bf(a) | ((u32)f2bf(b) << 16);
}
__device__ __forceinline__ void unpack8(uint4 v, float* f) {
    f[0] = bfu((u16)(v.x & 0xffffu)); f[1] = bfu((u16)(v.x >> 16));
    f[2] = bfu((u16)(v.y & 0xffffu)); f[3] = bfu((u16)(v.y >> 16));
    f[4] = bfu((u16)(v.z & 0xffffu)); f[5] = bfu((u16)(v.z >> 16));
    f[6] = bfu((u16)(v.w & 0xffffu)); f[7] = bfu((u16)(v.w >> 16));
}

#if __has_builtin(__builtin_amdgcn_global_load_lds)
#define HAVE_GLL 1
#else
#define HAVE_GLL 0
#endif

__device__ __forceinline__ void stage16(const void* g, void* ldsbase, int lane) {
#if HAVE_GLL
    typedef const __attribute__((address_space(1))) unsigned char ga_t;
    typedef __attribute__((address_space(3))) unsigned char la_t;
    __builtin_amdgcn_global_load_lds((ga_t*)(unsigned long long)g,
                                     (la_t*)(u32)(unsigned long long)ldsbase,
                                     16, 0, 0);
#else
    *reinterpret_cast<uint4*>((char*)ldsbase + lane * 16) =
        *reinterpret_cast<const uint4*>(g);
#endif
}

#define VW_IMPL(n) asm volatile("s_waitcnt vmcnt(" #n ")" ::: "memory")
#define VW(n) VW_IMPL(n)
#define LKW0 asm volatile("s_waitcnt lgkmcnt(0)" ::: "memory")
#define SBAR __builtin_amdgcn_sched_barrier(0)
#define WBAR __builtin_amdgcn_s_barrier()

// ---------------- 128x128-tile helpers (4 waves, 2x2) -------------------

__device__ __forceinline__ void stage_tile(const u16* src, int ld, u16* dst, int tid) {
    int w = tid >> 6, lane = tid & 63;
#pragma unroll
    for (int q = 0; q < 4; ++q) {
        int rbase = q * 32 + w * 8;
        int row = rbase + (lane >> 3);
        stage16(src + (size_t)row * ld + (lane & 7) * 8, dst + rbase * 64, lane);
    }
}

__device__ __forceinline__ void mfma_block(const u16* As, const u16* Bs,
                                           f32x4 acc[4][4], int wr, int wc, int lane) {
    int lr = lane >> 4, lc = lane & 15;
#pragma unroll
    for (int kc = 0; kc < 64; kc += 32) {
        bf16x8 av[4], bv[4];
#pragma unroll
        for (int it = 0; it < 4; ++it)
            av[it] = *(const bf16x8*)&As[(wr * 64 + it * 16 + lc) * 64 + kc + lr * 8];
#pragma unroll
        for (int nt = 0; nt < 4; ++nt)
            bv[nt] = *(const bf16x8*)&Bs[(wc * 64 + nt * 16 + lc) * 64 + kc + lr * 8];
#pragma unroll
        for (int it = 0; it < 4; ++it)
#pragma unroll
            for (int nt = 0; nt < 4; ++nt)
                acc[it][nt] = __builtin_amdgcn_mfma_f32_16x16x32_bf16(
                    av[it], bv[nt], acc[it][nt], 0, 0, 0);
    }
}

// ---------------------------- prep kernels ------------------------------

__global__ __launch_bounds__(256) void k_cast(const float* in, u16* out, int n) {
    int i = blockIdx.x * 256 + threadIdx.x;
    if (i < n) out[i] = f2bf(in[i]);
}

__global__ __launch_bounds__(256) void k_transposeB(const float* inA, const float* inB,
                                                    u16* outA, u16* outB, int R, int C) {
    const float* in = blockIdx.z ? inB : inA;
    u16* out = blockIdx.z ? outB : outA;
    __shared__ u16 tile[32][33];
    int c0 = blockIdx.x * 32, r0 = blockIdx.y * 32;
    int tx = threadIdx.x, ty = threadIdx.y;  // (32, 8)
#pragma unroll
    for (int dy = 0; dy < 32; dy += 8)
        tile[ty + dy][tx] = f2bf(in[(size_t)(r0 + ty + dy) * C + c0 + tx]);
    __syncthreads();
#pragma unroll
    for (int dy = 0; dy < 32; dy += 8)
        out[(size_t)(c0 + ty + dy) * R + r0 + tx] = tile[tx][ty + dy];
}

__global__ __launch_bounds__(256) void k_layer1(const float* states, const float* tptr,
                                                const float* dW1, const float* db1,
                                                const float* nW1, const float* nb1,
                                                u16* h1d, u16* h1n, u16* g1d) {
    __shared__ float xt[129][8];
    int blk = blockIdx.x, q = blockIdx.y, net = blockIdx.z, tid = threadIdx.x;
    float t = *tptr;
    for (int idx = tid; idx < 8 * 128; idx += 256) {
        int d = idx >> 3, s = idx & 7;
        xt[d][s] = states[(size_t)(blk * 8 + s) * 256 + d];
    }
    if (tid < 8) xt[128][tid] = t;
    __syncthreads();
    const float* W = net ? nW1 : dW1;
    const float* bi = net ? nb1 : db1;
    u16* H = net ? h1n : h1d;
    int o = q * 256 + tid;
    float acc[8] = {0.f, 0.f, 0.f, 0.f, 0.f, 0.f, 0.f, 0.f};
    for (int d = 0; d < 129; ++d) {
        float w = W[(size_t)d * 1024 + o];
        float4 xa = *(const float4*)&xt[d][0];
        float4 xb = *(const float4*)&xt[d][4];
        acc[0] += xa.x * w; acc[1] += xa.y * w; acc[2] += xa.z * w; acc[3] += xa.w * w;
        acc[4] += xb.x * w; acc[5] += xb.y * w; acc[6] += xb.z * w; acc[7] += xb.w * w;
    }
    float b = bi[o];
#pragma unroll
    for (int s = 0; s < 8; ++s) {
        float h = tanhf(acc[s] + b);
        H[(size_t)(blk * 8 + s) * 1024 + o] = f2bf(h);
        if (!net) g1d[(size_t)(blk * 8 + s) * 1024 + o] = f2bf(1.f - h * h);
    }
}

__global__ __launch_bounds__(256) void k_l2part(const u16* Ad, const u16* An,
                                                const u16* Wd, const u16* Wn,
                                                float* P) {
    int x = blockIdx.x;
    int nt = x & 7, ks = x >> 3;
    int mt = blockIdx.y, net = blockIdx.z;
    const u16* A = net ? An : Ad;
    const u16* W = net ? Wn : Wd;
    int n0 = nt * 128, row0 = mt * 128;
    int kbeg = ks * 512;
    __shared__ __align__(16) u16 As[128 * 64], Bs[128 * 64];
    int tid = threadIdx.x, w = tid >> 6, lane = tid & 63;
    int wr = w >> 1, wc = w & 1, lr = lane >> 4, lc = lane & 15;
    f32x4 acc[4][4];
#pragma unroll
    for (int a = 0; a < 4; ++a)
#pragma unroll
        for (int b2 = 0; b2 < 4; ++b2) { f32x4 zz = {0.f, 0.f, 0.f, 0.f}; acc[a][b2] = zz; }
    for (int k0 = kbeg; k0 < kbeg + 512; k0 += 64) {
        stage_tile(A + (size_t)row0 * 1024 + k0, 1024, As, tid);
        stage_tile(W + (size_t)n0 * 1024 + k0, 1024, Bs, tid);
        __syncthreads();
        mfma_block(As, Bs, acc, wr, wc, lane);
        __syncthreads();
    }
    float* dst = P + (size_t)(net * 2 + ks) * 1024 * 1024;
#pragma unroll
    for (int it = 0; it < 4; ++it)
#pragma unroll
        for (int nt2 = 0; nt2 < 4; ++nt2) {
            int col = n0 + wc * 64 + nt2 * 16 + lc;
#pragma unroll
            for (int r = 0; r < 4; ++r) {
                int row = row0 + wr * 64 + it * 16 + lr * 4 + r;
                dst[(size_t)row * 1024 + col] = acc[it][nt2][r];
            }
        }
}

__global__ __launch_bounds__(256) void k_h2fin(const float* P, const float* db2,
                                               const float* nb2, u16* h2d, u16* h2n) {
    int net = blockIdx.y;
    const float* b = net ? nb2 : db2;
    u16* H = net ? h2n : h2d;
    size_t idx = (size_t)blockIdx.x * 256 + threadIdx.x;  // < 1M
    int col = (int)(idx & 1023);
    const float* P0 = P + (size_t)(net * 2) * 1024 * 1024;
    const float* P1 = P + (size_t)(net * 2 + 1) * 1024 * 1024;
    H[idx] = f2bf(tanhf(P0[idx] + P1[idx] + b[col]));
}

__global__ __launch_bounds__(256) void k_l3part(const u16* Ad, const u16* An,
                                                const u16* Wd, const u16* Wn,
                                                float* P) {
    int ks = blockIdx.x, mt = blockIdx.y, net = blockIdx.z;
    const u16* A = net ? An : Ad;
    const u16* W = net ? Wn : Wd;
    int row0 = mt * 128, kbeg = ks * 256;
    __shared__ __align__(16) u16 As[128 * 64], Bs[128 * 64];
    int tid = threadIdx.x, w = tid >> 6, lane = tid & 63;
    int wr = w >> 1, wc = w & 1, lr = lane >> 4, lc = lane & 15;
    f32x4 acc[4][4];
#pragma unroll
    for (int a = 0; a < 4; ++a)
#pragma unroll
        for (int b2 = 0; b2 < 4; ++b2) { f32x4 zz = {0.f, 0.f, 0.f, 0.f}; acc[a][b2] = zz; }
    for (int k0 = kbeg; k0 < kbeg + 256; k0 += 64) {
        stage_tile(A + (size_t)row0 * 1024 + k0, 1024, As, tid);
        stage_tile(W + (size_t)k0, 1024, Bs, tid);
        __syncthreads();
        mfma_block(As, Bs, acc, wr, wc, lane);
        __syncthreads();
    }
    float* dst = P + (size_t)(net * 4 + ks) * 1024 * 128;
#pragma unroll
    for (int it = 0; it < 4; ++it)
#pragma unroll
        for (int nt2 = 0; nt2 < 4; ++nt2) {
            int col = wc * 64 + nt2 * 16 + lc;
#pragma unroll
            for (int r = 0; r < 4; ++r) {
                int row = row0 + wr * 64 + it * 16 + lr * 4 + r;
                dst[(size_t)row * 128 + col] = acc[it][nt2][r];
            }
        }
}

__global__ __launch_bounds__(256) void k_scaleA(const u16* dW1bf, const u16* g1d,
                                                u16* Asc, int c0) {
    int sl = blockIdx.x;
    size_t b = (size_t)(c0 + sl);
    const u16* g1 = g1d + b * 1024;
    u16* dst = Asc + (size_t)sl * (128 * 1024);
    int tid = threadIdx.x;
    for (int idx = tid; idx < 128 * 128; idx += 256) {
        int row = idx >> 7, jc = idx & 127;
        int j0 = jc * 8;
        uint4 wv = *(const uint4*)&dW1bf[(size_t)row * 1024 + j0];
        uint4 gv = *(const uint4*)&g1[j0];
        float wf[8], gf[8];
        unpack8(wv, wf);
        unpack8(gv, gf);
        uint4 o;
        o.x = pack2(wf[0] * gf[0], wf[1] * gf[1]);
        o.y = pack2(wf[2] * gf[2], wf[3] * gf[3]);
        o.z = pack2(wf[4] * gf[4], wf[5] * gf[5]);
        o.w = pack2(wf[6] * gf[6], wf[7] * gf[7]);
        *(uint4*)&dst[(size_t)row * 1024 + j0] = o;
    }
}

// ------------- 256x256 8-phase jac GEMM (BK=64, m201 schedule) ----------
// 512 thr = 8 waves (2M x 4N), wave tile 128x64 (8x4 frags of 16x16x32).
// LDS: 2 dbuf x {A[256x64], B[256x64]} bf16 = 128 KiB.
// Swizzle (r3, measured 0 conflicts): global SOURCE chunk c^(row&7), LDS
// linear via global_load_lds, ds_read chunk (kh*4+lr)^(row&7).
// Per K-tile u: 4 phases {ds-read subtile || stage one half-tile ->
// counted vmcnt (6/8/10/4, never 0 steady) -> barrier -> setprio+16 MFMA
// -> lgkmcnt(0) -> barrier}. Stage map: B(u+1)@ph1/ph2 (other dbuf),
// A(u+2)@ph3/ph4 (same dbuf, after A(u)'s last read in ph2).

__device__ __forceinline__ void stage_half(const u16* panel, int k0, int h,
                                           u16* dstTile, int tid) {
    int lane = tid & 63, w = tid >> 6;
#pragma unroll
    for (int q = 0; q < 2; ++q) {
        int D = q * 512 + tid;           // chunk 0..1023 within the half
        int r = D >> 3, c = D & 7;
        stage16(panel + (size_t)(h * 128 + r) * 1024 + k0 + ((c ^ (r & 7)) << 3),
                dstTile + (size_t)h * 8192 + (size_t)(q * 512 + w * 64) * 8, lane);
    }
}

__device__ __forceinline__ bf16x8 rdA(const u16* T, int wr, int m, int lc, int kq) {
    int row = wr * 128 + m * 16 + lc;
    return *(const bf16x8*)&T[row * 64 + ((kq ^ (row & 7)) << 3)];
}
__device__ __forceinline__ bf16x8 rdB(const u16* T, int wc, int n, int lc, int kq) {
    int row = wc * 64 + n * 16 + lc;
    return *(const bf16x8*)&T[row * 64 + ((kq ^ (row & 7)) << 3)];
}

#define MFMA16(AV, B0, B1, N0, N1)                                          \
    __builtin_amdgcn_s_setprio(1);                                          \
    _Pragma("unroll")                                                       \
    for (int m = 0; m < 8; ++m) {                                           \
        acc[m][N0] = __builtin_amdgcn_mfma_f32_16x16x32_bf16(AV[m], B0,     \
                                                             acc[m][N0], 0, 0, 0); \
        acc[m][N1] = __builtin_amdgcn_mfma_f32_16x16x32_bf16(AV[m], B1,     \
                                                             acc[m][N1], 0, 0, 0); \
    }                                                                       \
    __builtin_amdgcn_s_setprio(0);

template <bool STG_B, bool STG_A, bool TAIL0>
__device__ __forceinline__ void jac_iter(int u, u16 (*smA)[16384], u16 (*smB)[16384],
                                         const u16* Ap, const u16* Bp,
                                         f32x4 (&acc)[8][4], int tid,
                                         int wr, int wc, int lr, int lc) {
    u16* As_ = smA[u & 1];
    u16* Bs_ = smB[u & 1];
    u16* Bsn = smB[(u & 1) ^ 1];
    int k0 = u * 64;
    bf16x8 avA[8], avB[8], bv0, bv1;

    // -------- phase 1: read avA(kh0)+bv01(kh0); stage Bh0(u+1) --------
#pragma unroll
    for (int m = 0; m < 8; ++m) avA[m] = rdA(As_, wr, m, lc, lr);
    bv0 = rdB(Bs_, wc, 0, lc, lr);
    bv1 = rdB(Bs_, wc, 1, lc, lr);
    if (STG_B) stage_half(Bp, k0 + 64, 0, Bsn, tid);
    VW(6); SBAR; WBAR; SBAR;
    MFMA16(avA, bv0, bv1, 0, 1);
    SBAR; LKW0; SBAR; WBAR; SBAR;

    // -------- phase 2: read bv23(kh0)+avB(kh1); stage Bh1(u+1) --------
    bv0 = rdB(Bs_, wc, 2, lc, lr);
    bv1 = rdB(Bs_, wc, 3, lc, lr);
#pragma unroll
    for (int m = 0; m < 8; ++m) avB[m] = rdA(As_, wr, m, lc, 4 + lr);
    if (STG_B) stage_half(Bp, k0 + 64, 1, Bsn, tid);
    VW(8); SBAR; WBAR; SBAR;
    MFMA16(avA, bv0, bv1, 2, 3);
    SBAR; LKW0; SBAR; WBAR; SBAR;

    // -------- phase 3: read bv01(kh1); stage Ah0(u+2) (same dbuf) -----
    bv0 = rdB(Bs_, wc, 0, lc, 4 + lr);
    bv1 = rdB(Bs_, wc, 1, lc, 4 + lr);
    if (STG_A) stage_half(Ap, k0 + 128, 0, As_, tid);
    VW(10); SBAR; WBAR; SBAR;
    MFMA16(avB, bv0, bv1, 0, 1);
    SBAR; LKW0; SBAR; WBAR; SBAR;

    // -------- phase 4: read bv23(kh1); stage Ah1(u+2) -----------------
    bv0 = rdB(Bs_, wc, 2, lc, 4 + lr);
    bv1 = rdB(Bs_, wc, 3, lc, 4 + lr);
    if (STG_A) stage_half(Ap, k0 + 128, 1, As_, tid);
    if (TAIL0) { VW(0); } else { VW(4); }
    SBAR; WBAR; SBAR;
    MFMA16(avB, bv0, bv1, 2, 3);
    SBAR; LKW0; SBAR; WBAR; SBAR;
}

__global__ __launch_bounds__(512, 2) void k_jac256(const u16* Asc, const u16* W2T,
                                                   const u16* W3T, const u16* h2d,
                                                   float* Jpart, int c0, int CS) {
    __shared__ __align__(16) u16 smA[2][16384];
    __shared__ __align__(16) u16 smB[2][16384];
    int tid = threadIdx.x, lane = tid & 63, w = tid >> 6;
    int wr = w >> 2, wc = w & 3, lr = lane >> 4, lc = lane & 15;
    int nwg = 2 * CS;
    int hID = blockIdx.x;
    int lin = (hID & 7) * (nwg >> 3) + (hID >> 3);   // XCD-contiguous remap
    int mt = lin >> 2, nt = lin & 3;
    int n0 = nt * 256;
    const u16* Ap = Asc + (size_t)mt * 256 * 1024;
    const u16* Bp = W2T + (size_t)n0 * 1024;

    f32x4 acc[8][4];
#pragma unroll
    for (int m = 0; m < 8; ++m)
#pragma unroll
        for (int n = 0; n < 4; ++n) { f32x4 zz = {0.f, 0.f, 0.f, 0.f}; acc[m][n] = zz; }

    // prologue: tile0 (A+B, dbuf0) + tile1 A (dbuf1); B(1) staged in u=0
    stage_half(Ap, 0, 0, smA[0], tid);
    stage_half(Ap, 0, 1, smA[0], tid);
    stage_half(Bp, 0, 0, smB[0], tid);
    stage_half(Bp, 0, 1, smB[0], tid);
    stage_half(Ap, 64, 0, smA[1], tid);
    stage_half(Ap, 64, 1, smA[1], tid);
    VW(4); SBAR; WBAR; SBAR;

    for (int u = 0; u < 14; ++u)
        jac_iter<true, true, false>(u, smA, smB, Ap, Bp, acc, tid, wr, wc, lr, lc);
    jac_iter<true, false, true>(14, smA, smB, Ap, Bp, acc, tid, wr, wc, lr, lc);
    jac_iter<false, false, false>(15, smA, smB, Ap, Bp, acc, tid, wr, wc, lr, lc);

    // Fused diagonal contraction (r3/r4-verified mapping).
    int b = c0 + 2 * mt + wr;
    float g2v[4];
#pragma unroll
    for (int n = 0; n < 4; ++n) {
        int k2 = n0 + wc * 64 + n * 16 + lc;
        float h2 = bfu(h2d[(size_t)b * 1024 + k2]);
        g2v[n] = 1.f - h2 * h2;
    }
    float* jtmp = (float*)&smA[0][0];   // [4][256] floats
#pragma unroll
    for (int m = 0; m < 8; ++m) {
#pragma unroll
        for (int r = 0; r < 4; ++r) {
            int i = m * 16 + lr * 4 + r;
            float p = 0.f;
#pragma unroll
            for (int n = 0; n < 4; ++n) {
                int k2 = n0 + wc * 64 + n * 16 + lc;
                float w3 = bfu(W3T[(size_t)i * 1024 + k2]);
                p += acc[m][n][r] * g2v[n] * w3;
            }
#pragma unroll
            for (int msk = 1; msk < 16; msk <<= 1) p += __shfl_xor(p, msk, 64);
            if (lc == 0) jtmp[wc * 256 + wr * 128 + i] = p;
        }
    }
    __syncthreads();
    if (tid < 256) {
        float s = jtmp[tid] + jtmp[256 + tid] + jtmp[512 + tid] + jtmp[768 + tid];
        int bb = c0 + 2 * mt + (tid >> 7);
        Jpart[((size_t)bb * 4 + nt) * 128 + (tid & 127)] = s;
    }
}

// ------------------------------ finalize --------------------------------
__global__ __launch_bounds__(128) void k_final(const float* states, const float* Jpart,
                                               const float* L3part, const float* db3,
                                               const float* nb3, float* out) {
    int b = blockIdx.x, i = threadIdx.x;
    float jd = 0.f;
#pragma unroll
    for (int kb = 0; kb < 4; ++kb) jd += Jpart[((size_t)b * 4 + kb) * 128 + i];
    float mu = db3[i], qr = nb3[i];
#pragma unroll
    for (int ks = 0; ks < 4; ++ks) {
        mu += L3part[((size_t)(0 * 4 + ks) * 1024 + b) * 128 + i];
        qr += L3part[((size_t)(1 * 4 + ks) * 1024 + b) * 128 + i];
    }
    out[(size_t)b * 256 + i] = mu;
    float q = (qr > 20.f) ? qr : log1pf(expf(qr));
    float sig = states[(size_t)b * 256 + 128 + i];
    out[(size_t)b * 256 + 128 + i] = 2.f * jd * sig + q;
    float s1 = jd;
    float s2 = q / (sig + 1e-6f);
#pragma unroll
    for (int m = 32; m >= 1; m >>= 1) {
        s1 += __shfl_down(s1, m, 64);
        s2 += __shfl_down(s2, m, 64);
    }
    __shared__ float red[4];
    int wv = i >> 6, ln = i & 63;
    if (ln == 0) { red[wv * 2] = s1; red[wv * 2 + 1] = s2; }
    __syncthreads();
    if (i == 0) out[(size_t)NB * 256 + b] = -(red[0] + red[2]) + 0.5f * (red[1] + red[3]);
}

extern "C" void kernel_launch(void* const* d_in, const int* in_sizes, int n_in,
                              void* d_out, int out_size, void* d_ws, size_t ws_size,
                              hipStream_t stream) {
    (void)in_sizes; (void)n_in; (void)out_size;
    const float* states = (const float*)d_in[0];
    const float* tptr   = (const float*)d_in[1];
    const float* dW1 = (const float*)d_in[2];  const float* db1 = (const float*)d_in[3];
    const float* dW2 = (const float*)d_in[4];  const float* db2 = (const float*)d_in[5];
    const float* dW3 = (const float*)d_in[6];  const float* db3 = (const float*)d_in[7];
    const float* nW1 = (const float*)d_in[8];  const float* nb1 = (const float*)d_in[9];
    const float* nW2 = (const float*)d_in[10]; const float* nb2 = (const float*)d_in[11];
    const float* nW3 = (const float*)d_in[12]; const float* nb3 = (const float*)d_in[13];
    float* out = (float*)d_out;
    char* ws = (char*)d_ws;

    // workspace layout (bytes)
    u16* dW1bf = (u16*)(ws + 0);           //  128x1024 bf16     256 KiB
    u16* dW2T  = (u16*)(ws + 262144);      // 1024x1024 bf16 (T)   2 MiB
    u16* nW2T  = (u16*)(ws + 2359296);     //                      2 MiB
    u16* dW3T  = (u16*)(ws + 4456448);     //  128x1024 bf16 (T) 256 KiB
    u16* nW3T  = (u16*)(ws + 4718592);     //                    256 KiB
    u16* h1d   = (u16*)(ws + 4980736);     // 1024x1024 bf16       2 MiB
    u16* h1n   = (u16*)(ws + 7077888);
    u16* h2d   = (u16*)(ws + 9175040);
    u16* h2n   = (u16*)(ws + 11272192);
    u16* g1d   = (u16*)(ws + 13369344);    // 1024x1024 bf16       2 MiB
    float* Jpart  = (float*)(ws + 15466496);  // 1024x4x128 f32    2 MiB
    float* L3part = (float*)(ws + 17563648);  // 2x4x1024x128 f32  4 MiB
    float* H2part = (float*)(ws + 21757952);  // 2x2x1024x1024 f32 16 MiB
    u16* Asc   = (u16*)(ws + 38535168);    // CS x 128 x 1024 bf16 (chunked)
    const size_t ASC_OFF = 38535168;

    int CS = 1024;
    while (CS > 64 && ASC_OFF + (size_t)CS * 262144 > ws_size) CS >>= 1;

    k_cast<<<512, 256, 0, stream>>>(dW1, dW1bf, 128 * 1024);
    dim3 tb(32, 8);
    k_transposeB<<<dim3(32, 32, 2), tb, 0, stream>>>(dW2, nW2, dW2T, nW2T, 1024, 1024);
    k_transposeB<<<dim3(4, 32, 2), tb, 0, stream>>>(dW3, nW3, dW3T, nW3T, 1024, 128);
    k_layer1<<<dim3(128, 4, 2), 256, 0, stream>>>(states, tptr, dW1, db1, nW1, nb1,
                                                  h1d, h1n, g1d);
    k_l2part<<<dim3(16, 8, 2), 256, 0, stream>>>(h1d, h1n, dW2T, nW2T, H2part);
    k_h2fin<<<dim3(4096, 2), 256, 0, stream>>>(H2part, db2, nb2, h2d, h2n);
    k_l3part<<<dim3(4, 8, 2), 256, 0, stream>>>(h2d, h2n, dW3T, nW3T, L3part);
    for (int c0 = 0; c0 < NB; c0 += CS) {
        k_scaleA<<<CS, 256, 0, stream>>>(dW1bf, g1d, Asc, c0);
        k_jac256<<<2 * CS, 512, 0, stream>>>(Asc, dW2T, dW3T, h2d, Jpart, c0, CS);
    }
    k_final<<<1024, 128, 0, stream>>>(states, Jpart, L3part, db3, nb3, out);
}

// Round 6
// 388.226 us; speedup vs baseline: 1.1791x; 1.1454x over previous
//
#include <hip/hip_runtime.h>
#include <math.h>

typedef unsigned short u16;
typedef unsigned int u32;
typedef __bf16 bf16x8 __attribute__((ext_vector_type(8)));
typedef float f32x4 __attribute__((ext_vector_type(4)));

#define NB 1024   // batch
#define HID 1024

__device__ __forceinline__ float bfu(u16 u) { return __uint_as_float(((u32)u) << 16); }
__device__ __forceinline__ u16 f2bf(float f) {
    u32 u = __float_as_uint(f);
    return (u16)((u + 0x7fffu + ((u >> 16) & 1u)) >> 16);
}
// packed bf16-pair multiply: (a0*b0, a1*b1), round-half-up (cheap, ~0.5ulp)
__device__ __forceinline__ u32 mulbf2(u32 a, u32 b) {
    float a0 = __uint_as_float(a << 16), a1 = __uint_as_float(a & 0xffff0000u);
    float b0 = __uint_as_float(b << 16), b1 = __uint_as_float(b & 0xffff0000u);
    u32 u0 = __float_as_uint(a0 * b0), u1 = __float_as_uint(a1 * b1);
    return ((u0 + 0x8000u) >> 16) | ((u1 + 0x8000u) & 0xffff0000u);
}

#if __has_builtin(__builtin_amdgcn_global_load_lds)
#define HAVE_GLL 1
#else
#define HAVE_GLL 0
#endif

__device__ __forceinline__ void stage16(const void* g, void* ldsbase, int lane) {
#if HAVE_GLL
    typedef const __attribute__((address_space(1))) unsigned char ga_t;
    typedef __attribute__((address_space(3))) unsigned char la_t;
    __builtin_amdgcn_global_load_lds((ga_t*)(unsigned long long)g,
                                     (la_t*)(u32)(unsigned long long)ldsbase,
                                     16, 0, 0);
#else
    *reinterpret_cast<uint4*>((char*)ldsbase + lane * 16) =
        *reinterpret_cast<const uint4*>(g);
#endif
}

#define SBAR __builtin_amdgcn_sched_barrier(0)

// ---------------- 128x128-tile helpers (4 waves, 2x2) -------------------

__device__ __forceinline__ void stage_tile(const u16* src, int ld, u16* dst, int tid) {
    int w = tid >> 6, lane = tid & 63;
#pragma unroll
    for (int q = 0; q < 4; ++q) {
        int rbase = q * 32 + w * 8;
        int row = rbase + (lane >> 3);
        stage16(src + (size_t)row * ld + (lane & 7) * 8, dst + rbase * 64, lane);
    }
}

__device__ __forceinline__ void mfma_block(const u16* As, const u16* Bs,
                                           f32x4 acc[4][4], int wr, int wc, int lane) {
    int lr = lane >> 4, lc = lane & 15;
#pragma unroll
    for (int kc = 0; kc < 64; kc += 32) {
        bf16x8 av[4], bv[4];
#pragma unroll
        for (int it = 0; it < 4; ++it)
            av[it] = *(const bf16x8*)&As[(wr * 64 + it * 16 + lc) * 64 + kc + lr * 8];
#pragma unroll
        for (int nt = 0; nt < 4; ++nt)
            bv[nt] = *(const bf16x8*)&Bs[(wc * 64 + nt * 16 + lc) * 64 + kc + lr * 8];
#pragma unroll
        for (int it = 0; it < 4; ++it)
#pragma unroll
            for (int nt = 0; nt < 4; ++nt)
                acc[it][nt] = __builtin_amdgcn_mfma_f32_16x16x32_bf16(
                    av[it], bv[nt], acc[it][nt], 0, 0, 0);
    }
}

// ---------------------------- prep kernels ------------------------------

__global__ __launch_bounds__(256) void k_cast(const float* in, u16* out, int n) {
    int i = blockIdx.x * 256 + threadIdx.x;
    if (i < n) out[i] = f2bf(in[i]);
}

__global__ __launch_bounds__(256) void k_transposeB(const float* inA, const float* inB,
                                                    u16* outA, u16* outB, int R, int C) {
    const float* in = blockIdx.z ? inB : inA;
    u16* out = blockIdx.z ? outB : outA;
    __shared__ u16 tile[32][33];
    int c0 = blockIdx.x * 32, r0 = blockIdx.y * 32;
    int tx = threadIdx.x, ty = threadIdx.y;  // (32, 8)
#pragma unroll
    for (int dy = 0; dy < 32; dy += 8)
        tile[ty + dy][tx] = f2bf(in[(size_t)(r0 + ty + dy) * C + c0 + tx]);
    __syncthreads();
#pragma unroll
    for (int dy = 0; dy < 32; dy += 8)
        out[(size_t)(c0 + ty + dy) * R + r0 + tx] = tile[tx][ty + dy];
}

__global__ __launch_bounds__(256) void k_layer1(const float* states, const float* tptr,
                                                const float* dW1, const float* db1,
                                                const float* nW1, const float* nb1,
                                                u16* h1d, u16* h1n, u16* g1d) {
    __shared__ float xt[129][8];
    int blk = blockIdx.x, q = blockIdx.y, net = blockIdx.z, tid = threadIdx.x;
    float t = *tptr;
    for (int idx = tid; idx < 8 * 128; idx += 256) {
        int d = idx >> 3, s = idx & 7;
        xt[d][s] = states[(size_t)(blk * 8 + s) * 256 + d];
    }
    if (tid < 8) xt[128][tid] = t;
    __syncthreads();
    const float* W = net ? nW1 : dW1;
    const float* bi = net ? nb1 : db1;
    u16* H = net ? h1n : h1d;
    int o = q * 256 + tid;
    float acc[8] = {0.f, 0.f, 0.f, 0.f, 0.f, 0.f, 0.f, 0.f};
    for (int d = 0; d < 129; ++d) {
        float w = W[(size_t)d * 1024 + o];
        float4 xa = *(const float4*)&xt[d][0];
        float4 xb = *(const float4*)&xt[d][4];
        acc[0] += xa.x * w; acc[1] += xa.y * w; acc[2] += xa.z * w; acc[3] += xa.w * w;
        acc[4] += xb.x * w; acc[5] += xb.y * w; acc[6] += xb.z * w; acc[7] += xb.w * w;
    }
    float b = bi[o];
#pragma unroll
    for (int s = 0; s < 8; ++s) {
        float h = tanhf(acc[s] + b);
        H[(size_t)(blk * 8 + s) * 1024 + o] = f2bf(h);
        if (!net) g1d[(size_t)(blk * 8 + s) * 1024 + o] = f2bf(1.f - h * h);
    }
}

__global__ __launch_bounds__(256) void k_l2part(const u16* Ad, const u16* An,
                                                const u16* Wd, const u16* Wn,
                                                float* P) {
    int x = blockIdx.x;
    int nt = x & 7, ks = x >> 3;
    int mt = blockIdx.y, net = blockIdx.z;
    const u16* A = net ? An : Ad;
    const u16* W = net ? Wn : Wd;
    int n0 = nt * 128, row0 = mt * 128;
    int kbeg = ks * 512;
    __shared__ __align__(16) u16 As[128 * 64], Bs[128 * 64];
    int tid = threadIdx.x, w = tid >> 6, lane = tid & 63;
    int wr = w >> 1, wc = w & 1, lr = lane >> 4, lc = lane & 15;
    f32x4 acc[4][4];
#pragma unroll
    for (int a = 0; a < 4; ++a)
#pragma unroll
        for (int b2 = 0; b2 < 4; ++b2) { f32x4 zz = {0.f, 0.f, 0.f, 0.f}; acc[a][b2] = zz; }
    for (int k0 = kbeg; k0 < kbeg + 512; k0 += 64) {
        stage_tile(A + (size_t)row0 * 1024 + k0, 1024, As, tid);
        stage_tile(W + (size_t)n0 * 1024 + k0, 1024, Bs, tid);
        __syncthreads();
        mfma_block(As, Bs, acc, wr, wc, lane);
        __syncthreads();
    }
    float* dst = P + (size_t)(net * 2 + ks) * 1024 * 1024;
#pragma unroll
    for (int it = 0; it < 4; ++it)
#pragma unroll
        for (int nt2 = 0; nt2 < 4; ++nt2) {
            int col = n0 + wc * 64 + nt2 * 16 + lc;
#pragma unroll
            for (int r = 0; r < 4; ++r) {
                int row = row0 + wr * 64 + it * 16 + lr * 4 + r;
                dst[(size_t)row * 1024 + col] = acc[it][nt2][r];
            }
        }
}

__global__ __launch_bounds__(256) void k_h2fin(const float* P, const float* db2,
                                               const float* nb2, u16* h2d, u16* h2n) {
    int net = blockIdx.y;
    const float* b = net ? nb2 : db2;
    u16* H = net ? h2n : h2d;
    size_t idx = (size_t)blockIdx.x * 256 + threadIdx.x;  // < 1M
    int col = (int)(idx & 1023);
    const float* P0 = P + (size_t)(net * 2) * 1024 * 1024;
    const float* P1 = P + (size_t)(net * 2 + 1) * 1024 * 1024;
    H[idx] = f2bf(tanhf(P0[idx] + P1[idx] + b[col]));
}

__global__ __launch_bounds__(256) void k_l3part(const u16* Ad, const u16* An,
                                                const u16* Wd, const u16* Wn,
                                                float* P) {
    int ks = blockIdx.x, mt = blockIdx.y, net = blockIdx.z;
    const u16* A = net ? An : Ad;
    const u16* W = net ? Wn : Wd;
    int row0 = mt * 128, kbeg = ks * 256;
    __shared__ __align__(16) u16 As[128 * 64], Bs[128 * 64];
    int tid = threadIdx.x, w = tid >> 6, lane = tid & 63;
    int wr = w >> 1, wc = w & 1, lr = lane >> 4, lc = lane & 15;
    f32x4 acc[4][4];
#pragma unroll
    for (int a = 0; a < 4; ++a)
#pragma unroll
        for (int b2 = 0; b2 < 4; ++b2) { f32x4 zz = {0.f, 0.f, 0.f, 0.f}; acc[a][b2] = zz; }
    for (int k0 = kbeg; k0 < kbeg + 256; k0 += 64) {
        stage_tile(A + (size_t)row0 * 1024 + k0, 1024, As, tid);
        stage_tile(W + (size_t)k0, 1024, Bs, tid);
        __syncthreads();
        mfma_block(As, Bs, acc, wr, wc, lane);
        __syncthreads();
    }
    float* dst = P + (size_t)(net * 4 + ks) * 1024 * 128;
#pragma unroll
    for (int it = 0; it < 4; ++it)
#pragma unroll
        for (int nt2 = 0; nt2 < 4; ++nt2) {
            int col = wc * 64 + nt2 * 16 + lc;
#pragma unroll
            for (int r = 0; r < 4; ++r) {
                int row = row0 + wr * 64 + it * 16 + lr * 4 + r;
                dst[(size_t)row * 128 + col] = acc[it][nt2][r];
            }
        }
}

// ---------- 256x256 dbuf jac GEMM with FUSED g1-scale (no Asc) ----------
// 512 thr = 8 waves (2M x 4N), wave tile 128x64 (8x4 frags of 16x16x32).
// LDS: 2 dbuf x {A[256x64], B[256x64]} bf16 = 128 KiB.
// A-tile rows r: sample s = 2*mt + (r>>7), A[r][j] = dW1bf[r&127][j]*g1[s][j]
//   -- reg-staged: linear global loads (L2-hot, dW1bf is 256 KB total),
//   packed-bf16 scale, swizzled ds_write (chunk c^(r&7)); conflict-free
//   (8 lanes/row write a contiguous permuted 128B region).
// B-tile via global_load_lds with source-chunk swizzle (r3, 0 conflicts).
// Read side: chunk (kh*4+lr)^(row&7)  (compute256, r3-verified).

__device__ __forceinline__ void stage256(const u16* panel, int k0, u16* dst, int tid) {
    int lane = tid & 63, w = tid >> 6;
#pragma unroll
    for (int q = 0; q < 4; ++q) {
        int Dhalf = q * 4096 + w * 512 + lane * 8;   // dest offset in u16
        int row = Dhalf >> 6;                        // 64 u16 per row
        int chunk = (Dhalf >> 3) & 7;
        int src_chunk = chunk ^ (row & 7);
        stage16(panel + (size_t)row * 1024 + k0 + src_chunk * 8,
                dst + q * 4096 + w * 512, lane);
    }
}

struct ARegs { uint4 wv[4]; uint4 gv[4]; };

__device__ __forceinline__ void issueA(const u16* dW1bf, const u16* g1d, int mt,
                                       int k0, int tid, ARegs& ar) {
#pragma unroll
    for (int q = 0; q < 4; ++q) {
        int cid = q * 512 + tid;       // 16B-chunk id 0..2047
        int r = cid >> 3, c = cid & 7; // tile row, chunk-in-row
        ar.wv[q] = *(const uint4*)&dW1bf[(size_t)(r & 127) * 1024 + k0 + c * 8];
        ar.gv[q] = *(const uint4*)&g1d[(size_t)(2 * mt + (r >> 7)) * 1024 + k0 + c * 8];
    }
}

__device__ __forceinline__ void writeA(u16* As_, int tid, const ARegs& ar) {
#pragma unroll
    for (int q = 0; q < 4; ++q) {
        int cid = q * 512 + tid;
        int r = cid >> 3, c = cid & 7;
        uint4 o;
        o.x = mulbf2(ar.wv[q].x, ar.gv[q].x);
        o.y = mulbf2(ar.wv[q].y, ar.gv[q].y);
        o.z = mulbf2(ar.wv[q].z, ar.gv[q].z);
        o.w = mulbf2(ar.wv[q].w, ar.gv[q].w);
        *(uint4*)&As_[r * 64 + ((c ^ (r & 7)) << 3)] = o;
    }
}

__device__ __forceinline__ void compute256(const u16* As, const u16* Bs,
                                           f32x4 acc[8][4], int wr, int wc, int lane) {
    int lr = lane >> 4, lc = lane & 15;
#pragma unroll
    for (int kh = 0; kh < 2; ++kh) {
        bf16x8 av[8], bv[4];
#pragma unroll
        for (int m = 0; m < 8; ++m) {
            int row = wr * 128 + m * 16 + lc;
            int chunk = (kh * 4 + lr) ^ (row & 7);
            av[m] = *(const bf16x8*)&As[row * 64 + chunk * 8];
        }
#pragma unroll
        for (int n = 0; n < 4; ++n) {
            int row = wc * 64 + n * 16 + lc;
            int chunk = (kh * 4 + lr) ^ (row & 7);
            bv[n] = *(const bf16x8*)&Bs[row * 64 + chunk * 8];
        }
#pragma unroll
        for (int m = 0; m < 8; ++m)
#pragma unroll
            for (int n = 0; n < 4; ++n)
                acc[m][n] = __builtin_amdgcn_mfma_f32_16x16x32_bf16(
                    av[m], bv[n], acc[m][n], 0, 0, 0);
    }
}

__global__ __launch_bounds__(512, 2) void k_jacf(const u16* dW1bf, const u16* g1d,
                                                 const u16* W2T, const u16* W3T,
                                                 const u16* h2d, float* Jpart) {
    __shared__ __align__(16) u16 smem[2][2][16384];  // [dbuf][A,B][256*64]
    int tid = threadIdx.x, lane = tid & 63, w = tid >> 6;
    int wr = w >> 2, wc = w & 3, lr = lane >> 4, lc = lane & 15;
    int hID = blockIdx.x;                            // 0..2047
    int lin = (hID & 7) * 256 + (hID >> 3);          // XCD-contiguous remap
    int mt = lin >> 2, nt = lin & 3;                 // mt 0..511, nt 0..3
    int n0 = nt * 256;
    const u16* Bp = W2T + (size_t)n0 * 1024;

    f32x4 acc[8][4];
#pragma unroll
    for (int m = 0; m < 8; ++m)
#pragma unroll
        for (int n = 0; n < 4; ++n) { f32x4 zz = {0.f, 0.f, 0.f, 0.f}; acc[m][n] = zz; }

    ARegs ar;
    // prologue: tile 0
    issueA(dW1bf, g1d, mt, 0, tid, ar);
    stage256(Bp, 0, &smem[0][1][0], tid);
    writeA(&smem[0][0][0], tid, ar);
    __syncthreads();

    for (int t = 0; t < 16; ++t) {
        int p = t & 1;
        if (t < 15) {
            issueA(dW1bf, g1d, mt, (t + 1) * 64, tid, ar);
            stage256(Bp, (t + 1) * 64, &smem[p ^ 1][1][0], tid);
        }
        SBAR;   // pin staging issue before compute
        __builtin_amdgcn_s_setprio(1);
        compute256(&smem[p][0][0], &smem[p][1][0], acc, wr, wc, lane);
        __builtin_amdgcn_s_setprio(0);
        if (t < 15) writeA(&smem[p ^ 1][0][0], tid, ar);  // write-late (T14)
        __syncthreads();
    }

    // Fused diagonal contraction (r3/r5-verified mapping).
    int b = 2 * mt + wr;
    float g2v[4];
#pragma unroll
    for (int n = 0; n < 4; ++n) {
        int k2 = n0 + wc * 64 + n * 16 + lc;
        float h2 = bfu(h2d[(size_t)b * 1024 + k2]);
        g2v[n] = 1.f - h2 * h2;
    }
    float* jtmp = (float*)&smem[0][0][0];   // [4][256] floats
#pragma unroll
    for (int m = 0; m < 8; ++m) {
#pragma unroll
        for (int r = 0; r < 4; ++r) {
            int i = m * 16 + lr * 4 + r;
            float p = 0.f;
#pragma unroll
            for (int n = 0; n < 4; ++n) {
                int k2 = n0 + wc * 64 + n * 16 + lc;
                float w3 = bfu(W3T[(size_t)i * 1024 + k2]);
                p += acc[m][n][r] * g2v[n] * w3;
            }
#pragma unroll
            for (int msk = 1; msk < 16; msk <<= 1) p += __shfl_xor(p, msk, 64);
            if (lc == 0) jtmp[wc * 256 + wr * 128 + i] = p;
        }
    }
    __syncthreads();
    if (tid < 256) {
        float s = jtmp[tid] + jtmp[256 + tid] + jtmp[512 + tid] + jtmp[768 + tid];
        int bb = 2 * mt + (tid >> 7);
        Jpart[((size_t)bb * 4 + nt) * 128 + (tid & 127)] = s;
    }
}

// ------------------------------ finalize --------------------------------
__global__ __launch_bounds__(128) void k_final(const float* states, const float* Jpart,
                                               const float* L3part, const float* db3,
                                               const float* nb3, float* out) {
    int b = blockIdx.x, i = threadIdx.x;
    float jd = 0.f;
#pragma unroll
    for (int kb = 0; kb < 4; ++kb) jd += Jpart[((size_t)b * 4 + kb) * 128 + i];
    float mu = db3[i], qr = nb3[i];
#pragma unroll
    for (int ks = 0; ks < 4; ++ks) {
        mu += L3part[((size_t)(0 * 4 + ks) * 1024 + b) * 128 + i];
        qr += L3part[((size_t)(1 * 4 + ks) * 1024 + b) * 128 + i];
    }
    out[(size_t)b * 256 + i] = mu;
    float q = (qr > 20.f) ? qr : log1pf(expf(qr));
    float sig = states[(size_t)b * 256 + 128 + i];
    out[(size_t)b * 256 + 128 + i] = 2.f * jd * sig + q;
    float s1 = jd;
    float s2 = q / (sig + 1e-6f);
#pragma unroll
    for (int m = 32; m >= 1; m >>= 1) {
        s1 += __shfl_down(s1, m, 64);
        s2 += __shfl_down(s2, m, 64);
    }
    __shared__ float red[4];
    int wv = i >> 6, ln = i & 63;
    if (ln == 0) { red[wv * 2] = s1; red[wv * 2 + 1] = s2; }
    __syncthreads();
    if (i == 0) out[(size_t)NB * 256 + b] = -(red[0] + red[2]) + 0.5f * (red[1] + red[3]);
}

extern "C" void kernel_launch(void* const* d_in, const int* in_sizes, int n_in,
                              void* d_out, int out_size, void* d_ws, size_t ws_size,
                              hipStream_t stream) {
    (void)in_sizes; (void)n_in; (void)out_size; (void)ws_size;
    const float* states = (const float*)d_in[0];
    const float* tptr   = (const float*)d_in[1];
    const float* dW1 = (const float*)d_in[2];  const float* db1 = (const float*)d_in[3];
    const float* dW2 = (const float*)d_in[4];  const float* db2 = (const float*)d_in[5];
    const float* dW3 = (const float*)d_in[6];  const float* db3 = (const float*)d_in[7];
    const float* nW1 = (const float*)d_in[8];  const float* nb1 = (const float*)d_in[9];
    const float* nW2 = (const float*)d_in[10]; const float* nb2 = (const float*)d_in[11];
    const float* nW3 = (const float*)d_in[12]; const float* nb3 = (const float*)d_in[13];
    float* out = (float*)d_out;
    char* ws = (char*)d_ws;

    // workspace layout (bytes)
    u16* dW1bf = (u16*)(ws + 0);           //  128x1024 bf16     256 KiB
    u16* dW2T  = (u16*)(ws + 262144);      // 1024x1024 bf16 (T)   2 MiB
    u16* nW2T  = (u16*)(ws + 2359296);     //                      2 MiB
    u16* dW3T  = (u16*)(ws + 4456448);     //  128x1024 bf16 (T) 256 KiB
    u16* nW3T  = (u16*)(ws + 4718592);     //                    256 KiB
    u16* h1d   = (u16*)(ws + 4980736);     // 1024x1024 bf16       2 MiB
    u16* h1n   = (u16*)(ws + 7077888);
    u16* h2d   = (u16*)(ws + 9175040);
    u16* h2n   = (u16*)(ws + 11272192);
    u16* g1d   = (u16*)(ws + 13369344);    // 1024x1024 bf16       2 MiB
    float* Jpart  = (float*)(ws + 15466496);  // 1024x4x128 f32    2 MiB
    float* L3part = (float*)(ws + 17563648);  // 2x4x1024x128 f32  4 MiB
    float* H2part = (float*)(ws + 21757952);  // 2x2x1024x1024 f32 16 MiB

    k_cast<<<512, 256, 0, stream>>>(dW1, dW1bf, 128 * 1024);
    dim3 tb(32, 8);
    k_transposeB<<<dim3(32, 32, 2), tb, 0, stream>>>(dW2, nW2, dW2T, nW2T, 1024, 1024);
    k_transposeB<<<dim3(4, 32, 2), tb, 0, stream>>>(dW3, nW3, dW3T, nW3T, 1024, 128);
    k_layer1<<<dim3(128, 4, 2), 256, 0, stream>>>(states, tptr, dW1, db1, nW1, nb1,
                                                  h1d, h1n, g1d);
    k_l2part<<<dim3(16, 8, 2), 256, 0, stream>>>(h1d, h1n, dW2T, nW2T, H2part);
    k_h2fin<<<dim3(4096, 2), 256, 0, stream>>>(H2part, db2, nb2, h2d, h2n);
    k_l3part<<<dim3(4, 8, 2), 256, 0, stream>>>(h2d, h2n, dW3T, nW3T, L3part);
    k_jacf<<<2048, 512, 0, stream>>>(dW1bf, g1d, dW2T, dW3T, h2d, Jpart);
    k_final<<<1024, 128, 0, stream>>>(states, Jpart, L3part, db3, nb3, out);
}